// Round 1
// baseline (407.730 us; speedup 1.0000x reference)
//
#include <hip/hip_runtime.h>

// Batched SPD 64x64 matrix log: degree-18 Chebyshev/Clenshaw, split-bf16 MFMA.
// R4 (from 435.1 us baseline) — attacks VALU issue + dependency latency:
//  1. Split via native RNE bf16 casts (v_cvt_pk_bf16_f32 pairs): ~13 -> ~3 ops/val.
//  2. LDS row layout [64 hi | 64 lo | 8 pad] (272 B stride, 16B-aligned) so each
//     B-fragment is ONE ds_read_b128 (8 reads/step vs 16 b64), bank-uniform.
//  3. Clenshaw "ck*I - b_{k+2}" folded into MFMA C-in seed (kills epilogue
//     sub/cndmask/add, ends Bpp live range before the MFMA region).
//  4. Dual accumulator chains (slices 0,1 -> acc0; 2,3 -> acc1): dependent-MFMA
//     chain 12 -> 6; one 16-wide add to merge.
//  5. constexpr Chebyshev coefficients (compile-time double sqrt/ln): no tid0
//     transcendentals, no cf[] LDS, one barrier removed, ck inline literal.
// Indexing (verified vs m74/m101 layouts): A[m=lane&31][k=(lane>>5)*8+j],
// B[k=(lane>>5)*8+j][n=lane&31], C/D row=(t&3)+8*(t>>2)+4*(lane>>5), col=lane&31.
// LDS stores Bc[n][k] (valid: b_k symmetric); k-coordinate is GLOBAL row (R2 fix).

#define NCH 18
#define EV_LO 0.0995f
#define EV_HI 5.6f
#define ROWB 136   // bf16 elems per LDS row: 64 hi + 64 lo + 8 pad = 272 B

typedef __bf16 bf16x8 __attribute__((ext_vector_type(8)));
typedef __bf16 bf16x4 __attribute__((ext_vector_type(4)));
typedef float f32x16 __attribute__((ext_vector_type(16)));

union BU { __bf16 b; unsigned short u; };
__device__ __forceinline__ float bf2f(__bf16 h) {
  BU t; t.b = h; return __uint_as_float(((unsigned)t.u) << 16);
}
__device__ __forceinline__ void split2(float v, __bf16& h, __bf16& l) {
  h = (__bf16)v;                    // native RNE (cvt_pk pairs under -O3)
  l = (__bf16)(v - bf2f(h));        // exact residual, then RNE
}

// ---- compile-time Chebyshev coefficients of log on [EV_LO, EV_HI] ----
constexpr double csqrt_(double x) {
  double g = x > 1.0 ? x : 1.0;
  for (int i = 0; i < 64; ++i) g = 0.5 * (g + x / g);
  return g;
}
constexpr double cln_(double x) {
  double z = (x - 1.0) / (x + 1.0), z2 = z * z, t = z, s = 0.0;
  for (int k = 0; k < 100; ++k) { s += t / (2.0 * k + 1.0); t *= z2; }
  return 2.0 * s;
}
struct CFA { float v[NCH + 1]; };
constexpr CFA mkcf() {
  CFA a{};
  const double c = 0.5 * ((double)EV_LO + (double)EV_HI);
  const double d = 0.5 * ((double)EV_HI - (double)EV_LO);
  const double s = csqrt_((double)EV_LO * (double)EV_HI);
  const double r = d / (c + s);
  a.v[0] = (float)cln_(0.5 * (c + s));
  double rk = 1.0;
  for (int k = 1; k <= NCH; ++k) {
    rk *= r;
    a.v[k] = (float)(((k & 1) ? 2.0 : -2.0) * rk / (double)k);
  }
  return a;
}
constexpr CFA CF = mkcf();

#define MFMA32(a, b, c) __builtin_amdgcn_mfma_f32_32x32x16_bf16(a, b, c, 0, 0, 0)

__global__ __launch_bounds__(256, 4)
void logeig_cheb_mfma(const float* __restrict__ x, float* __restrict__ out) {
  __shared__ __align__(16) __bf16 BB[2][64 * ROWB];

  const int tid  = threadIdx.x;
  const int lane = tid & 63;
  const int wid  = tid >> 6;
  const int half = lane >> 5;          // 0/1
  const int ln   = lane & 31;
  const int r0   = (wid >> 1) << 5;    // tile row base
  const int c0   = (wid & 1) << 5;     // tile col base
  const int colg = c0 + ln;            // output column (C/D: col = lane&31)

  const float cc = 0.5f * (EV_LO + EV_HI);
  const float dd = 0.5f * (EV_HI - EV_LO);
  const float scale = 2.0f / dd;

  const float* Ag = x + (size_t)blockIdx.x * 4096;

  // ---- A-operand fragments of Y2 (rows r0+ln), split hi/lo, in regs ----
  union F8 { bf16x8 v8; bf16x4 v4[2]; };
  F8 Yh[4], Yl[4];
  {
    const int row = r0 + ln;
    const float* arow = Ag + row * 64;
    #pragma unroll
    for (int s = 0; s < 4; ++s) {
      const int k0 = 16 * s + 8 * half;
      #pragma unroll
      for (int j = 0; j < 8; ++j) {
        float v = arow[k0 + j];
        if (row == k0 + j) v -= cc;
        v *= scale;
        __bf16 h, l; split2(v, h, l);
        Yh[s].v8[j] = h; Yl[s].v8[j] = l;
      }
    }
  }

  // ---- init Clenshaw state in C/D-layout registers ----
  float Bpp[16], Bcur[16];
  {
    const float cN = CF.v[NCH], cN1 = CF.v[NCH - 1];
    #pragma unroll
    for (int t = 0; t < 16; ++t) {
      const int rg = r0 + (t & 3) + 8 * (t >> 2) + 4 * half;
      float v = Ag[rg * 64 + colg];
      const bool dg = (rg == colg);
      if (dg) v -= cc;
      v *= scale;                          // Y2 element
      Bpp[t]  = dg ? cN : 0.0f;            // b_N = cN I
      Bcur[t] = cN * v + (dg ? cN1 : 0.0f);// b_{N-1} = cN1 I + cN*Y2
    }
  }

  // write split(Bcur) into buffer 0: row = colg, k-coordinate GLOBAL (r0 + ...)
  {
    __bf16* wp = &BB[0][colg * ROWB];
    #pragma unroll
    for (int g = 0; g < 4; ++g) {
      const int kb = r0 + 8 * g + 4 * half;
      bf16x4 wh, wl;
      #pragma unroll
      for (int q = 0; q < 4; ++q) {
        __bf16 h, l; split2(Bcur[4 * g + q], h, l);
        wh[q] = h; wl[q] = l;
      }
      *(bf16x4*)&wp[kb]      = wh;
      *(bf16x4*)&wp[64 + kb] = wl;
    }
  }

  int cur = 0;

  // ---- Clenshaw main loop: b_k = ck I + Y2*b_{k+1} - b_{k+2} ----
  #pragma unroll
  for (int k = NCH - 2; k >= 1; --k) {
    __syncthreads();
    const __bf16* rp = &BB[cur][colg * ROWB];
    f32x16 acc0, acc1;
    const float ck = CF.v[k];
    #pragma unroll
    for (int t = 0; t < 16; ++t) {           // seed: acc0 = ck*I - b_{k+2}
      const int rg = r0 + (t & 3) + 8 * (t >> 2) + 4 * half;
      acc0[t] = ((rg == colg) ? ck : 0.0f) - Bpp[t];
      acc1[t] = 0.0f;
      Bpp[t] = Bcur[t];                      // pure renaming after unroll
    }
    #pragma unroll
    for (int s = 0; s < 4; ++s) {
      const int ko = 16 * s + 8 * half;
      bf16x8 fh = *(const bf16x8*)&rp[ko];        // one ds_read_b128
      bf16x8 fl = *(const bf16x8*)&rp[64 + ko];   // one ds_read_b128
      if (s < 2) {
        acc0 = MFMA32(Yh[s].v8, fh, acc0);
        acc0 = MFMA32(Yh[s].v8, fl, acc0);
        acc0 = MFMA32(Yl[s].v8, fh, acc0);
      } else {
        acc1 = MFMA32(Yh[s].v8, fh, acc1);
        acc1 = MFMA32(Yh[s].v8, fl, acc1);
        acc1 = MFMA32(Yl[s].v8, fh, acc1);
      }
    }
    #pragma unroll
    for (int t = 0; t < 16; ++t) Bcur[t] = acc0[t] + acc1[t];

    __bf16* wp = &BB[cur ^ 1][colg * ROWB];
    #pragma unroll
    for (int g = 0; g < 4; ++g) {
      const int kb = r0 + 8 * g + 4 * half;      // GLOBAL row coordinate
      bf16x4 wh, wl;
      #pragma unroll
      for (int q = 0; q < 4; ++q) {
        __bf16 h, l; split2(Bcur[4 * g + q], h, l);
        wh[q] = h; wl[q] = l;
      }
      *(bf16x4*)&wp[kb]      = wh;
      *(bf16x4*)&wp[64 + kb] = wl;
    }
    cur ^= 1;
  }

  // ---- final: out = c0 I + 0.5*Y2*b1 - b2 ----
  __syncthreads();
  {
    const __bf16* rp = &BB[cur][colg * ROWB];
    f32x16 acc0 = {}, acc1 = {};
    #pragma unroll
    for (int s = 0; s < 4; ++s) {
      const int ko = 16 * s + 8 * half;
      bf16x8 fh = *(const bf16x8*)&rp[ko];
      bf16x8 fl = *(const bf16x8*)&rp[64 + ko];
      if (s < 2) {
        acc0 = MFMA32(Yh[s].v8, fh, acc0);
        acc0 = MFMA32(Yh[s].v8, fl, acc0);
        acc0 = MFMA32(Yl[s].v8, fh, acc0);
      } else {
        acc1 = MFMA32(Yh[s].v8, fh, acc1);
        acc1 = MFMA32(Yh[s].v8, fl, acc1);
        acc1 = MFMA32(Yl[s].v8, fh, acc1);
      }
    }
    float* Og = out + (size_t)blockIdx.x * 4096;
    const float c0f = CF.v[0];
    #pragma unroll
    for (int t = 0; t < 16; ++t) {
      const int rg = r0 + (t & 3) + 8 * (t >> 2) + 4 * half;
      Og[rg * 64 + colg] = fmaf(0.5f, acc0[t] + acc1[t],
                                ((rg == colg) ? c0f : 0.0f) - Bpp[t]);
    }
  }
}

extern "C" void kernel_launch(void* const* d_in, const int* in_sizes, int n_in,
                              void* d_out, int out_size, void* d_ws, size_t ws_size,
                              hipStream_t stream) {
  const float* x = (const float*)d_in[0];
  float* outp = (float*)d_out;
  const int nmat = in_sizes[0] / 4096;   // 8192 matrices of 64x64
  logeig_cheb_mfma<<<nmat, 256, 0, stream>>>(x, outp);
}

// Round 2
// 371.457 us; speedup vs baseline: 1.0977x; 1.0977x over previous
//
#include <hip/hip_runtime.h>

// Batched SPD 64x64 matrix log: degree-18 Chebyshev/Clenshaw, split-bf16 MFMA.
// R5 — LDS-free / barrier-free restructure:
//   Each wave owns a full 64x32 COLUMN STRIPE (2 waves per matrix, was 4 waves
//   with 32x32 tiles). The wave computes both 32x32 row-tiles of its stripe
//   (full K=64 reduction), so the next Clenshaw step's B operand is entirely
//   its OWN C/D output — no inter-wave exchange, no LDS, no __syncthreads.
//   The C/D(row-groups-of-4 per half) -> B(k-runs-of-8 per half) layout fixup
//   is done in-register with v_permlane32_swap_b32:
//     swap(pack(group 2s), pack(group 2s+1)) -> (frag d0, frag d2)  [both halves]
//   (group q = C/D elements t=4q..4q+3 = global rows 8q+4*half+p; slice s needs
//    rows 16s+8*half..+7 = own group + partner-half group, verified algebra.)
// Y2 A-fragments (full matrix, hi+lo split) live in registers: 64 VGPRs.
// ~210 VGPR total -> 2 waves/SIMD; waves fully independent so no convoy stalls.
// Numerics identical to R4: same RNE hi/lo split, same 3-pass MFMA
// (Yh*Bh + Yh*Bl + Yl*Bh), same Clenshaw order, same constexpr coefficients.

#define NCH 18
#define EV_LO 0.0995f
#define EV_HI 5.6f

typedef __bf16 bf16x8 __attribute__((ext_vector_type(8)));
typedef float f32x16 __attribute__((ext_vector_type(16)));

union BU { __bf16 b; unsigned short u; };
__device__ __forceinline__ float bf2f(__bf16 h) {
  BU t; t.b = h; return __uint_as_float(((unsigned)t.u) << 16);
}
__device__ __forceinline__ unsigned pk2(float lo, float hi) {  // 2xf32 -> bf16x2 (RNE)
  union { __bf16 h[2]; unsigned u; } t;
  t.h[0] = (__bf16)lo; t.h[1] = (__bf16)hi;
  return t.u;
}
__device__ __forceinline__ float lo2f(unsigned u) { return __uint_as_float(u << 16); }
__device__ __forceinline__ float hi2f(unsigned u) { return __uint_as_float(u & 0xffff0000u); }

// ---- compile-time Chebyshev coefficients of log on [EV_LO, EV_HI] ----
constexpr double csqrt_(double x) {
  double g = x > 1.0 ? x : 1.0;
  for (int i = 0; i < 64; ++i) g = 0.5 * (g + x / g);
  return g;
}
constexpr double cln_(double x) {
  double z = (x - 1.0) / (x + 1.0), z2 = z * z, t = z, s = 0.0;
  for (int k = 0; k < 100; ++k) { s += t / (2.0 * k + 1.0); t *= z2; }
  return 2.0 * s;
}
struct CFA { float v[NCH + 1]; };
constexpr CFA mkcf() {
  CFA a{};
  const double c = 0.5 * ((double)EV_LO + (double)EV_HI);
  const double d = 0.5 * ((double)EV_HI - (double)EV_LO);
  const double s = csqrt_((double)EV_LO * (double)EV_HI);
  const double r = d / (c + s);
  a.v[0] = (float)cln_(0.5 * (c + s));
  double rk = 1.0;
  for (int k = 1; k <= NCH; ++k) {
    rk *= r;
    a.v[k] = (float)(((k & 1) ? 2.0 : -2.0) * rk / (double)k);
  }
  return a;
}
constexpr CFA CF = mkcf();

#define MFMA32(a, b, c) __builtin_amdgcn_mfma_f32_32x32x16_bf16(a, b, c, 0, 0, 0)

struct Frags { bf16x8 h[4], l[4]; };

// Build B fragments (B[k=16s+8*half+j][n=colg]) for all 4 K-slices from the
// wave's own C/D-layout f32 state, via hi/lo bf16 split + permlane32 swaps.
__device__ __forceinline__ void build_frags(const float (&Bc)[2][16], Frags& F) {
  #pragma unroll
  for (int s = 0; s < 4; ++s) {
    const int qa = 2 * s, qb = 2 * s + 1;
    const int ra = qa >> 2, ia = 4 * (qa & 3);
    const int rb = qb >> 2, ib = 4 * (qb & 3);
    const float a0 = Bc[ra][ia], a1 = Bc[ra][ia + 1], a2 = Bc[ra][ia + 2], a3 = Bc[ra][ia + 3];
    const float b0 = Bc[rb][ib], b1 = Bc[rb][ib + 1], b2 = Bc[rb][ib + 2], b3 = Bc[rb][ib + 3];
    unsigned A0 = pk2(a0, a1), A1 = pk2(a2, a3);
    unsigned B0 = pk2(b0, b1), B1 = pk2(b2, b3);
    unsigned A0l = pk2(a0 - lo2f(A0), a1 - hi2f(A0));
    unsigned A1l = pk2(a2 - lo2f(A1), a3 - hi2f(A1));
    unsigned B0l = pk2(b0 - lo2f(B0), b1 - hi2f(B0));
    unsigned B1l = pk2(b2 - lo2f(B1), b3 - hi2f(B1));
    // swap(X,Y): X' = [X_lo, Y_lo(from lanes 0-31)], Y' = [X_hi(from lanes 32-63), Y_hi]
    asm("v_permlane32_swap_b32 %0, %1" : "+v"(A0), "+v"(B0));
    asm("v_permlane32_swap_b32 %0, %1" : "+v"(A1), "+v"(B1));
    asm("v_permlane32_swap_b32 %0, %1" : "+v"(A0l), "+v"(B0l));
    asm("v_permlane32_swap_b32 %0, %1" : "+v"(A1l), "+v"(B1l));
    union { unsigned u[4]; bf16x8 v; } th, tl;
    th.u[0] = A0; th.u[1] = A1; th.u[2] = B0; th.u[3] = B1;   // d0,d1,d2,d3
    tl.u[0] = A0l; tl.u[1] = A1l; tl.u[2] = B0l; tl.u[3] = B1l;
    F.h[s] = th.v; F.l[s] = tl.v;
  }
}

__global__ __launch_bounds__(256, 2)
void logeig_cheb_mfma(const float* __restrict__ x, float* __restrict__ out, int nmat) {
  const int tid  = threadIdx.x;
  const int lane = tid & 63;
  const int wid  = tid >> 6;
  const int half = lane >> 5;          // 0/1
  const int ln   = lane & 31;
  const int c0   = (wid & 1) << 5;     // column-stripe base
  const int colg = c0 + ln;            // this lane's column (C/D + B: n = lane&31)
  const long mat = (long)blockIdx.x * 2 + (wid >> 1);
  if (mat >= nmat) return;             // wave-uniform; no barriers anywhere

  const float cc = 0.5f * (EV_LO + EV_HI);
  const float dd = 0.5f * (EV_HI - EV_LO);
  const float scale = 2.0f / dd;
  const float* Ag = x + mat * 4096;

  // ---- full Y2 as A-fragments (both row-tiles rt, all 4 K-slices), hi/lo ----
  // A layout: A[m = lane&31][k = (lane>>5)*8 + j]; global row = 32*rt + ln.
  bf16x8 Yh[2][4], Yl[2][4];
  {
    #pragma unroll
    for (int rt = 0; rt < 2; ++rt) {
      const int row = 32 * rt + ln;
      const float* arow = Ag + row * 64;
      #pragma unroll
      for (int s = 0; s < 4; ++s) {
        const int k0 = 16 * s + 8 * half;
        const float4 v0 = *(const float4*)&arow[k0];
        const float4 v1 = *(const float4*)&arow[k0 + 4];
        const float vv[8] = {v0.x, v0.y, v0.z, v0.w, v1.x, v1.y, v1.z, v1.w};
        #pragma unroll
        for (int j = 0; j < 8; ++j) {
          float v = vv[j];
          if (row == k0 + j) v -= cc;
          v *= scale;
          __bf16 h = (__bf16)v;
          Yh[rt][s][j] = h;
          Yl[rt][s][j] = (__bf16)(v - bf2f(h));
        }
      }
    }
  }

  // ---- init Clenshaw state (C/D layout: row=(t&3)+8*(t>>2)+4*half, col=colg) ----
  float Bcur[2][16], Bpp[2][16];
  {
    const float cN = CF.v[NCH], cN1 = CF.v[NCH - 1];
    #pragma unroll
    for (int rt = 0; rt < 2; ++rt) {
      #pragma unroll
      for (int t = 0; t < 16; ++t) {
        const int rg = 32 * rt + (t & 3) + 8 * (t >> 2) + 4 * half;
        float v = Ag[rg * 64 + colg];
        const bool dg = (rg == colg);
        if (dg) v -= cc;
        v *= scale;                           // Y2 element
        Bpp[rt][t]  = dg ? cN : 0.0f;         // b_N = cN I
        Bcur[rt][t] = cN * v + (dg ? cN1 : 0.0f);  // b_{N-1} = cN1 I + cN*Y2
      }
    }
  }

  // ---- Clenshaw main loop: b_k = ck I + Y2*b_{k+1} - b_{k+2} (no barriers) ----
  #pragma unroll
  for (int k = NCH - 2; k >= 1; --k) {
    Frags F;
    build_frags(Bcur, F);
    const float ck = CF.v[k];
    f32x16 acc[2];
    #pragma unroll
    for (int rt = 0; rt < 2; ++rt) {
      #pragma unroll
      for (int t = 0; t < 16; ++t) {
        const int rg = 32 * rt + (t & 3) + 8 * (t >> 2) + 4 * half;
        acc[rt][t] = ((rg == colg) ? ck : 0.0f) - Bpp[rt][t];  // seed = ck I - b_{k+2}
        Bpp[rt][t] = Bcur[rt][t];             // rename (full unroll -> no copies)
      }
    }
    #pragma unroll
    for (int s = 0; s < 4; ++s) {             // interleave the two tile chains
      acc[0] = MFMA32(Yh[0][s], F.h[s], acc[0]);
      acc[1] = MFMA32(Yh[1][s], F.h[s], acc[1]);
      acc[0] = MFMA32(Yh[0][s], F.l[s], acc[0]);
      acc[1] = MFMA32(Yh[1][s], F.l[s], acc[1]);
      acc[0] = MFMA32(Yl[0][s], F.h[s], acc[0]);
      acc[1] = MFMA32(Yl[1][s], F.h[s], acc[1]);
    }
    #pragma unroll
    for (int rt = 0; rt < 2; ++rt)
      #pragma unroll
      for (int t = 0; t < 16; ++t) Bcur[rt][t] = acc[rt][t];
  }

  // ---- final: out = c0 I + 0.5*Y2*b1 - b2 ----
  {
    Frags F;
    build_frags(Bcur, F);
    f32x16 acc[2] = {};
    #pragma unroll
    for (int s = 0; s < 4; ++s) {
      acc[0] = MFMA32(Yh[0][s], F.h[s], acc[0]);
      acc[1] = MFMA32(Yh[1][s], F.h[s], acc[1]);
      acc[0] = MFMA32(Yh[0][s], F.l[s], acc[0]);
      acc[1] = MFMA32(Yh[1][s], F.l[s], acc[1]);
      acc[0] = MFMA32(Yl[0][s], F.h[s], acc[0]);
      acc[1] = MFMA32(Yl[1][s], F.h[s], acc[1]);
    }
    float* Og = out + mat * 4096;
    const float c0f = CF.v[0];
    #pragma unroll
    for (int rt = 0; rt < 2; ++rt) {
      #pragma unroll
      for (int t = 0; t < 16; ++t) {
        const int rg = 32 * rt + (t & 3) + 8 * (t >> 2) + 4 * half;
        Og[rg * 64 + colg] = fmaf(0.5f, acc[rt][t],
                                  ((rg == colg) ? c0f : 0.0f) - Bpp[rt][t]);
      }
    }
  }
}

extern "C" void kernel_launch(void* const* d_in, const int* in_sizes, int n_in,
                              void* d_out, int out_size, void* d_ws, size_t ws_size,
                              hipStream_t stream) {
  const float* x = (const float*)d_in[0];
  float* outp = (float*)d_out;
  const int nmat = in_sizes[0] / 4096;   // 8192 matrices of 64x64
  const int grid = (nmat + 1) / 2;       // 2 matrices per 256-thread block
  logeig_cheb_mfma<<<grid, 256, 0, stream>>>(x, outp, nmat);
}